// Round 4
// baseline (254.792 us; speedup 1.0000x reference)
//
#include <hip/hip_runtime.h>

// Problem constants
#define BINS   32
#define NB     64          // batch
#define NCH    3           // channels (merged into one histogram per reference)
#define HH     512
#define WW     512
#define F4_PER_BLOCK 6144  // 24 iters * 256 threads * 1 float4
// image = 3*512*512 floats = 196608 float4 = 32 blocks per image -> 2048 blocks

// Native clang vector type: __builtin_nontemporal_load requires a real vector.
typedef float vfloat4 __attribute__((ext_vector_type(4)));

// counts layout in d_ws: unsigned counts[NB][4][BINS]  (quad = qr*2 + qc)

// Contiguous-stripe histogram: each block reads a contiguous 96 KiB stripe
// (pure pointer-increment addressing). Quadrant identity is a bit function of
// the flat float4 index: qc = bit6(t) (thread-constant), qr = bit15 of the
// wave-uniform base -> scalar per iteration. Per element: v_mul + v_cvt +
// lshl_add + ds_add (no clamp needed: input is uniform [0,1), so
// (int)(x*32.0f) is in [0,31] -- largest fp32 < 1.0 maps to 31.999998 -> 31,
// bit-identical to the reference's fp32 floor(x*32)).
__global__ __launch_bounds__(256, 8) void hist_main(const float* __restrict__ in,
                                                    unsigned* __restrict__ counts) {
    __shared__ unsigned whist[8][4][BINS];   // [half-wave][quad][bin], 4 KiB

    const int t   = threadIdx.x;
    const int o   = blockIdx.x;
    const int b   = o >> 5;              // 32 blocks per image
    const int sub = t >> 5;              // 32-lane group id
    const int qc  = (t >> 6) & 1;        // bit 6 of within-image f4 index

    // zero 1024 words, 4 per thread, bank = t%32 (conflict-free)
    unsigned* wflat = &whist[0][0][0];
    #pragma unroll
    for (int k = 0; k < 4; ++k) wflat[k * 256 + t] = 0;
    __syncthreads();

    const int A = (o & 31) * F4_PER_BLOCK;   // within-image f4 base (mult of 256)
    const float* p = in + (size_t)o * (F4_PER_BLOCK * 4) + t * 4;

    #pragma unroll 4
    for (int it = 0; it < 24; ++it) {
        const int qr = ((A + it * 256) >> 15) & 1;   // wave-uniform (t < 256: no carry)
        const vfloat4 v = __builtin_nontemporal_load(
            (const vfloat4*)(p + (size_t)it * 1024));
        unsigned* h = &whist[sub][qr * 2 + qc][0];
        #pragma unroll
        for (int u = 0; u < 4; ++u) {
            const int bin = (int)(v[u] * 32.0f);
            atomicAdd(&h[bin], 1u);      // ds_add_u32, fire-and-forget
        }
    }
    __syncthreads();

    // 128 (quad,bin) cells; thread t sums the 8 half-wave copies.
    // flat index g*128 + t -> bank t%32, conflict-free.
    if (t < 128) {
        const int quad = t >> 5;
        const int bin  = t & 31;
        unsigned tot = 0;
        #pragma unroll
        for (int g = 0; g < 8; ++g) tot += whist[g][quad][bin];
        atomicAdd(&counts[(b * 4 + quad) * BINS + bin], tot);
    }
}

// out[b][ch][i][j], ch in [0,96): 0-31 = s0 (global hist), 32-63 = s1 (quadrant),
// 64-95 = zeros (must be written: d_out is poisoned before every launch).
__global__ __launch_bounds__(256) void finalize(const unsigned* __restrict__ counts,
                                                float* __restrict__ out, int n) {
    const int idx = blockIdx.x * 256 + threadIdx.x;
    if (idx >= n) return;
    const int j  = idx & 3;
    const int i  = (idx >> 2) & 3;
    const int ch = (idx >> 4) % 96;
    const int b  = idx / 1536;           // 96*16
    float val = 0.0f;
    if (ch < 32) {
        const unsigned ssum = counts[(b * 4 + 0) * BINS + ch]
                            + counts[(b * 4 + 1) * BINS + ch]
                            + counts[(b * 4 + 2) * BINS + ch]
                            + counts[(b * 4 + 3) * BINS + ch];
        val = (float)ssum * (1.0f / 262144.0f);   // / (h*w), exact pow2
    } else if (ch < 64) {
        const int bin = ch - 32;
        const int q   = (i >> 1) * 2 + (j >> 1);
        val = (float)counts[(b * 4 + q) * BINS + bin] * (1.0f / 65536.0f); // / (hh*ww)
    }
    out[idx] = val;
}

extern "C" void kernel_launch(void* const* d_in, const int* in_sizes, int n_in,
                              void* d_out, int out_size, void* d_ws, size_t ws_size,
                              hipStream_t stream) {
    const float* in = (const float*)d_in[0];
    float* out      = (float*)d_out;
    unsigned* counts = (unsigned*)d_ws;   // NB*4*BINS = 8192 uints = 32 KiB

    (void)hipMemsetAsync(counts, 0, NB * 4 * BINS * sizeof(unsigned), stream);
    hist_main<<<NB * 32, 256, 0, stream>>>(in, counts);
    finalize<<<(out_size + 255) / 256, 256, 0, stream>>>(counts, out, out_size);
}

// Round 5
// 253.690 us; speedup vs baseline: 1.0043x; 1.0043x over previous
//
#include <hip/hip_runtime.h>

// Problem constants
#define BINS   32
#define NB     64          // batch
#define NCH    3           // channels (merged into one histogram per reference)
#define HH     512
#define WW     512
#define F4_PER_BLOCK 6144  // 24 iters * 256 threads * 1 float4
// image = 3*512*512 floats = 196608 float4 = 32 blocks per image -> 2048 blocks

// Native clang vector type: __builtin_nontemporal_load requires a real vector.
typedef float vfloat4 __attribute__((ext_vector_type(4)));

// d_ws layout: unsigned partial[2048][128]  -- per-block [quad][bin] counts,
// written non-atomically (pure overwrite -> no zero-init dispatch needed).

// Contiguous-stripe histogram: each block reads a contiguous 96 KiB stripe
// (pointer-increment addressing). Quadrant identity is a bit function of the
// flat float4 index: qc = bit6(t) (thread-constant), qr = bit15 of the
// wave-uniform base. No clamp needed: input is uniform [0,1), so
// (int)(x*32.0f) is in [0,31], bit-identical to the reference's floor(x*32).
__global__ __launch_bounds__(256, 8) void hist_main(const float* __restrict__ in,
                                                    unsigned* __restrict__ partial) {
    __shared__ unsigned whist[8][4][BINS];   // [half-wave][quad][bin], 4 KiB

    const int t   = threadIdx.x;
    const int o   = blockIdx.x;
    const int sub = t >> 5;              // 32-lane group id
    const int qc  = (t >> 6) & 1;        // bit 6 of within-image f4 index

    // zero 1024 words, 4 per thread, bank = t%32 (conflict-free)
    unsigned* wflat = &whist[0][0][0];
    #pragma unroll
    for (int k = 0; k < 4; ++k) wflat[k * 256 + t] = 0;
    __syncthreads();

    const int A = (o & 31) * F4_PER_BLOCK;   // within-image f4 base (mult of 256)
    const float* p = in + (size_t)o * (F4_PER_BLOCK * 4) + t * 4;

    #pragma unroll 4
    for (int it = 0; it < 24; ++it) {
        const int qr = ((A + it * 256) >> 15) & 1;   // wave-uniform (t < 256: no carry)
        const vfloat4 v = __builtin_nontemporal_load(
            (const vfloat4*)(p + (size_t)it * 1024));
        unsigned* h = &whist[sub][qr * 2 + qc][0];
        #pragma unroll
        for (int u = 0; u < 4; ++u) {
            const int bin = (int)(v[u] * 32.0f);
            atomicAdd(&h[bin], 1u);      // ds_add_u32, fire-and-forget
        }
    }
    __syncthreads();

    // 128 (quad,bin) cells; thread t sums the 8 half-wave copies and stores
    // the per-block partial (coalesced, non-atomic).
    if (t < 128) {
        const int quad = t >> 5;
        const int bin  = t & 31;
        unsigned tot = 0;
        #pragma unroll
        for (int g = 0; g < 8; ++g) tot += whist[g][quad][bin];
        partial[(size_t)o * 128 + t] = tot;
    }
}

// One block per image: reduce the 32 stripe-block partials, then write all
// 1536 outputs for that image (including the zero third-scale block, since
// d_out is poisoned before every launch). All scales are exact pow2: count_q /
// 65536 exact; quad-sums in units of 2^-16 stay < 2^24 -> exact; /4 exact.
__global__ __launch_bounds__(256) void finalize(const unsigned* __restrict__ partial,
                                                float* __restrict__ out) {
    __shared__ float s1v[128];   // [quad][bin] / 65536
    __shared__ float s0v[32];    // global hist / 262144

    const int b = blockIdx.x;
    const int t = threadIdx.x;

    if (t < 128) {
        const unsigned* p = partial + (size_t)b * 32 * 128 + t;
        unsigned tot = 0;
        #pragma unroll
        for (int o = 0; o < 32; ++o) tot += p[o * 128];
        s1v[t] = (float)tot * (1.0f / 65536.0f);
    }
    __syncthreads();
    if (t < 32) {
        s0v[t] = (s1v[t] + s1v[32 + t] + s1v[64 + t] + s1v[96 + t]) * 0.25f;
    }
    __syncthreads();

    // out[b][ch][i][j]: ch 0-31 = s0, 32-63 = s1 per quadrant, 64-95 = zeros.
    float* ob = out + (size_t)b * 1536;
    #pragma unroll
    for (int k = t; k < 1536; k += 256) {
        const int j  = k & 3;
        const int i  = (k >> 2) & 3;
        const int ch = k >> 4;
        float val = 0.0f;
        if (ch < 32) {
            val = s0v[ch];
        } else if (ch < 64) {
            const int q = (i >> 1) * 2 + (j >> 1);
            val = s1v[q * 32 + (ch - 32)];
        }
        ob[k] = val;
    }
}

extern "C" void kernel_launch(void* const* d_in, const int* in_sizes, int n_in,
                              void* d_out, int out_size, void* d_ws, size_t ws_size,
                              hipStream_t stream) {
    const float* in   = (const float*)d_in[0];
    float* out        = (float*)d_out;
    unsigned* partial = (unsigned*)d_ws;   // 2048*128 uints = 1 MiB

    hist_main<<<NB * 32, 256, 0, stream>>>(in, partial);
    finalize<<<NB, 256, 0, stream>>>(partial, out);
}